// Round 1
// baseline (328.532 us; speedup 1.0000x reference)
//
#include <hip/hip_runtime.h>
#include <hip/hip_bf16.h>

// MHA forward: N=2, S=T=2048, E=1024, H=16, HD=64. All-bf16 MFMA pipeline.
typedef __bf16 bf16x8 __attribute__((ext_vector_type(8)));
typedef __bf16 bf16x4 __attribute__((ext_vector_type(4)));
typedef float  f32x4  __attribute__((ext_vector_type(4)));

#define MFMA16(a, b, c) __builtin_amdgcn_mfma_f32_16x16x32_bf16((a), (b), (c), 0, 0, 0)

constexpr int NB = 2, SEQ = 2048, EMB = 1024, NHEAD = 16, HD = 64;

// ---------------------------------------------------------------------------
// Weight transpose + cast: WT[n][k] = (bf16)W[k][n], 1024x1024, z selects matrix
// ---------------------------------------------------------------------------
__global__ __launch_bounds__(256)
void wtrans(const float* __restrict__ W0, const float* __restrict__ W1,
            const float* __restrict__ W2, const float* __restrict__ W3,
            __bf16* __restrict__ T0, __bf16* __restrict__ T1,
            __bf16* __restrict__ T2, __bf16* __restrict__ T3)
{
    __shared__ float tile[32][33];  // +1 pad: conflict-free transposed reads
    const float* W; __bf16* T;
    const int z = blockIdx.z;
    if (z == 0)      { W = W0; T = T0; }
    else if (z == 1) { W = W1; T = T1; }
    else if (z == 2) { W = W2; T = T2; }
    else             { W = W3; T = T3; }
    const int kb = blockIdx.x * 32, nb = blockIdx.y * 32;
    const int c = threadIdx.x & 31, r0 = threadIdx.x >> 5;  // c:0..31, r0:0..7
#pragma unroll
    for (int i = 0; i < 4; ++i)
        tile[r0 + 8*i][c] = W[(size_t)(kb + r0 + 8*i)*1024 + nb + c];
    __syncthreads();
#pragma unroll
    for (int i = 0; i < 4; ++i)
        T[(size_t)(nb + r0 + 8*i)*1024 + kb + c] = (__bf16)tile[c][r0 + 8*i];
}

// ---------------------------------------------------------------------------
// 128x128 tile GEMM, K=1024, BK=64. C[m][n] = sum_k A[m][k]*Bt[n][k] + bias[n].
// MODE 0: A fp32 (query), C -> q  [nh][s][64] bf16
// MODE 1: A fp32 (key),   C -> k  [nh][t][64] bf16
// MODE 2: A fp32 (value), C -> vT [nh][64][t] bf16  (transposed for PV B-frags)
// MODE 3: A bf16 (attnO), C -> out [m][n] fp32
// ---------------------------------------------------------------------------
template<int MODE>
__global__ __launch_bounds__(256)
void gemm128(const void* __restrict__ Aptr, const __bf16* __restrict__ Bt,
             const float* __restrict__ bias, void* __restrict__ Cptr)
{
    __shared__ __attribute__((aligned(16))) __bf16 As[128][72];  // +8 pad
    __shared__ __attribute__((aligned(16))) __bf16 Bs[128][72];
    const int tid = threadIdx.x;
    const int lane = tid & 63, wave = tid >> 6;
    const int wm = wave >> 1, wn = wave & 1;
    const int quad = lane >> 4, l16 = lane & 15;
    const int bm = blockIdx.x, bn = blockIdx.y;

    const int srow = tid >> 3;        // 0..31 (staging row)
    const int scol = (tid & 7) * 8;   // 0..56 (staging k-chunk)

    f32x4 acc[4][4] = {};

    for (int k0 = 0; k0 < 1024; k0 += 64) {
        __syncthreads();
        if constexpr (MODE < 3) {
            const float* A = (const float*)Aptr;
#pragma unroll
            for (int i = 0; i < 4; ++i) {
                const int r = srow + 32*i;
                const float4* src = (const float4*)(A + (size_t)(bm*128 + r)*1024 + k0 + scol);
                float4 f0 = src[0], f1 = src[1];
                bf16x8 v;
                v[0]=(__bf16)f0.x; v[1]=(__bf16)f0.y; v[2]=(__bf16)f0.z; v[3]=(__bf16)f0.w;
                v[4]=(__bf16)f1.x; v[5]=(__bf16)f1.y; v[6]=(__bf16)f1.z; v[7]=(__bf16)f1.w;
                *(bf16x8*)&As[r][scol] = v;
            }
        } else {
            const __bf16* A = (const __bf16*)Aptr;
#pragma unroll
            for (int i = 0; i < 4; ++i) {
                const int r = srow + 32*i;
                *(bf16x8*)&As[r][scol] = *(const bf16x8*)(A + (size_t)(bm*128 + r)*1024 + k0 + scol);
            }
        }
#pragma unroll
        for (int i = 0; i < 4; ++i) {
            const int r = srow + 32*i;
            *(bf16x8*)&Bs[r][scol] = *(const bf16x8*)(Bt + (size_t)(bn*128 + r)*1024 + k0 + scol);
        }
        __syncthreads();
#pragma unroll
        for (int ks = 0; ks < 2; ++ks) {
            bf16x8 af[4], bfr[4];
#pragma unroll
            for (int mt = 0; mt < 4; ++mt)
                af[mt] = *(const bf16x8*)&As[wm*64 + mt*16 + l16][ks*32 + quad*8];
#pragma unroll
            for (int nt = 0; nt < 4; ++nt)
                bfr[nt] = *(const bf16x8*)&Bs[wn*64 + nt*16 + l16][ks*32 + quad*8];
#pragma unroll
            for (int mt = 0; mt < 4; ++mt)
#pragma unroll
                for (int nt = 0; nt < 4; ++nt)
                    acc[mt][nt] = MFMA16(af[mt], bfr[nt], acc[mt][nt]);
        }
    }

    // Epilogue. C-layout: col = l16 (per n-tile), rows = quad*4 + r (per m-tile).
#pragma unroll
    for (int nt = 0; nt < 4; ++nt) {
        const int n = bn*128 + wn*64 + nt*16 + l16;
        const float bv = bias[n];
#pragma unroll
        for (int mt = 0; mt < 4; ++mt) {
            const int mbase = bm*128 + wm*64 + mt*16 + quad*4;
            f32x4 v = acc[mt][nt];
            if constexpr (MODE == 0 || MODE == 1) {
                __bf16* C = (__bf16*)Cptr;
                const int h = n >> 6, d = n & 63;
#pragma unroll
                for (int r = 0; r < 4; ++r) {
                    const int m = mbase + r;
                    const int nb = m >> 11, s = m & 2047;
                    C[(size_t)(nb*NHEAD + h)*(SEQ*HD) + (size_t)s*HD + d] = (__bf16)(v[r] + bv);
                }
            } else if constexpr (MODE == 2) {
                __bf16* C = (__bf16*)Cptr;
                const int h = n >> 6, d = n & 63;
                const int nb = mbase >> 11, s = mbase & 2047;  // 4 consecutive s, 8B-aligned
                bf16x4 o;
#pragma unroll
                for (int r = 0; r < 4; ++r) o[r] = (__bf16)(v[r] + bv);
                *(bf16x4*)&C[(size_t)(nb*NHEAD + h)*(SEQ*HD) + (size_t)d*SEQ + s] = o;
            } else {
                float* C = (float*)Cptr;
#pragma unroll
                for (int r = 0; r < 4; ++r)
                    C[(size_t)(mbase + r)*1024 + n] = v[r] + bv;
            }
        }
    }
}

// ---------------------------------------------------------------------------
// Flash attention: 64 Q-rows/block (16 per wave), K/V tiles of 128, online
// softmax. q,k: [nh][t][64]; vT: [nh][64][t]; O: [N,S,E] bf16.
// ---------------------------------------------------------------------------
__global__ __launch_bounds__(256)
void attn64(const __bf16* __restrict__ qg, const __bf16* __restrict__ kg,
            const __bf16* __restrict__ vg, __bf16* __restrict__ Og)
{
    __shared__ __attribute__((aligned(16))) __bf16 Qs[64][72];
    __shared__ __attribute__((aligned(16))) __bf16 Ks[128][72];
    __shared__ __attribute__((aligned(16))) __bf16 Vs[64][136];      // vT tile [d][t]
    __shared__ __attribute__((aligned(16))) __bf16 Ps[4][16][136];   // per-wave P

    const int tid = threadIdx.x, lane = tid & 63, wave = tid >> 6;
    const int quad = lane >> 4, l16 = lane & 15;
    const int nh = blockIdx.y;
    const int q0 = blockIdx.x * 64;
    const __bf16* qb = qg + (size_t)nh * (SEQ*HD);
    const __bf16* kb = kg + (size_t)nh * (SEQ*HD);
    const __bf16* vb = vg + (size_t)nh * (SEQ*HD);

    {   // stage Q 64x64 once
        const int r = tid >> 3, c = (tid & 7) * 8;
#pragma unroll
        for (int i = 0; i < 2; ++i)
            *(bf16x8*)&Qs[r + 32*i][c] = *(const bf16x8*)(qb + (size_t)(q0 + r + 32*i)*HD + c);
    }
    __syncthreads();
    bf16x8 qf[2];  // Q A-frags, loop-invariant
#pragma unroll
    for (int ks = 0; ks < 2; ++ks)
        qf[ks] = *(const bf16x8*)&Qs[wave*16 + l16][ks*32 + quad*8];

    f32x4 oacc[4] = {};
    float mrow[4], lrow[4];
#pragma unroll
    for (int r = 0; r < 4; ++r) { mrow[r] = -__builtin_inff(); lrow[r] = 0.f; }

    for (int t0 = 0; t0 < SEQ; t0 += 128) {
        __syncthreads();
        {   // stage K 128x64
            const int r = tid >> 3, c = (tid & 7)*8;
#pragma unroll
            for (int i = 0; i < 4; ++i)
                *(bf16x8*)&Ks[r + 32*i][c] = *(const bf16x8*)(kb + (size_t)(t0 + r + 32*i)*HD + c);
        }
        {   // stage vT 64x128
            const int d = tid >> 4, c = (tid & 15)*8;
#pragma unroll
            for (int i = 0; i < 4; ++i)
                *(bf16x8*)&Vs[d + 16*i][c] = *(const bf16x8*)(vb + (size_t)(d + 16*i)*SEQ + t0 + c);
        }
        __syncthreads();

        // S = Q K^T (raw, scale folded into softmax). Wave: 16 x 128.
        f32x4 sc[8] = {};
#pragma unroll
        for (int ks = 0; ks < 2; ++ks)
#pragma unroll
            for (int nt = 0; nt < 8; ++nt) {
                bf16x8 kf = *(const bf16x8*)&Ks[nt*16 + l16][ks*32 + quad*8];
                sc[nt] = MFMA16(qf[ks], kf, sc[nt]);
            }

        // Online softmax; C-layout rows m = quad*4+r, cols across 16 lanes.
        float mnew[4], alpha[4], rsum[4];
#pragma unroll
        for (int r = 0; r < 4; ++r) {
            float mx = sc[0][r];
#pragma unroll
            for (int nt = 1; nt < 8; ++nt) mx = fmaxf(mx, sc[nt][r]);
#pragma unroll
            for (int off = 1; off < 16; off <<= 1)
                mx = fmaxf(mx, __shfl_xor(mx, off, 64));
            mnew[r] = fmaxf(mrow[r], 0.125f * mx);
            alpha[r] = __expf(mrow[r] - mnew[r]);
            mrow[r] = mnew[r];
            rsum[r] = 0.f;
        }
#pragma unroll
        for (int nt = 0; nt < 8; ++nt)
#pragma unroll
            for (int r = 0; r < 4; ++r) {
                float p = __expf(__builtin_fmaf(0.125f, sc[nt][r], -mnew[r]));
                rsum[r] += p;
                Ps[wave][quad*4 + r][nt*16 + l16] = (__bf16)p;
            }
#pragma unroll
        for (int r = 0; r < 4; ++r) {
            float sm = rsum[r];
#pragma unroll
            for (int off = 1; off < 16; off <<= 1)
                sm += __shfl_xor(sm, off, 64);
            lrow[r] = lrow[r]*alpha[r] + sm;
#pragma unroll
            for (int dt = 0; dt < 4; ++dt) oacc[dt][r] *= alpha[r];
        }
        // Per-wave P region: no barrier needed, just drain LDS writes.
        asm volatile("s_waitcnt lgkmcnt(0)" ::: "memory");
        // O += P V.  A-frag from Ps (row=l16, k=t), B-frag from Vs[d][t].
#pragma unroll
        for (int kk = 0; kk < 4; ++kk) {
            bf16x8 pf = *(const bf16x8*)&Ps[wave][l16][kk*32 + quad*8];
#pragma unroll
            for (int dt = 0; dt < 4; ++dt) {
                bf16x8 vf = *(const bf16x8*)&Vs[dt*16 + l16][kk*32 + quad*8];
                oacc[dt] = MFMA16(pf, vf, oacc[dt]);
            }
        }
    }

    const int nb = nh >> 4, h = nh & 15;
#pragma unroll
    for (int r = 0; r < 4; ++r) {
        const float inv = 1.0f / lrow[r];
        const int srow2 = q0 + wave*16 + quad*4 + r;
#pragma unroll
        for (int dt = 0; dt < 4; ++dt)
            Og[(size_t)(nb*SEQ + srow2)*EMB + h*HD + dt*16 + l16] = (__bf16)(oacc[dt][r] * inv);
    }
}

// ---------------------------------------------------------------------------
extern "C" void kernel_launch(void* const* d_in, const int* in_sizes, int n_in,
                              void* d_out, int out_size, void* d_ws, size_t ws_size,
                              hipStream_t stream)
{
    const float* query = (const float*)d_in[0];
    const float* key_  = (const float*)d_in[1];
    const float* value = (const float*)d_in[2];
    const float* Wq = (const float*)d_in[3];
    const float* bq = (const float*)d_in[4];
    const float* Wk = (const float*)d_in[5];
    const float* bk = (const float*)d_in[6];
    const float* Wv = (const float*)d_in[7];
    const float* bv = (const float*)d_in[8];
    const float* Wo = (const float*)d_in[9];
    const float* bo = (const float*)d_in[10];
    float* out = (float*)d_out;

    // Workspace layout (40 MB total, all bf16):
    constexpr size_t SZW = 1024u*1024u;   // one weight matrix
    constexpr size_t SZX = 4096u*1024u;   // one activation tensor
    __bf16* ws  = (__bf16*)d_ws;
    __bf16* WqT = ws;
    __bf16* WkT = WqT + SZW;
    __bf16* WvT = WkT + SZW;
    __bf16* WoT = WvT + SZW;
    __bf16* qh  = WoT + SZW;   // [nh][s][64]
    __bf16* kh  = qh + SZX;    // [nh][t][64]
    __bf16* vTh = kh + SZX;    // [nh][64][t]
    __bf16* Oh  = vTh + SZX;   // [N,S,E]

    wtrans<<<dim3(32, 32, 4), 256, 0, stream>>>(Wq, Wk, Wv, Wo, WqT, WkT, WvT, WoT);
    gemm128<0><<<dim3(32, 8), 256, 0, stream>>>(query, WqT, bq, qh);
    gemm128<1><<<dim3(32, 8), 256, 0, stream>>>(key_,  WkT, bk, kh);
    gemm128<2><<<dim3(32, 8), 256, 0, stream>>>(value, WvT, bv, vTh);
    attn64<<<dim3(32, 32), 256, 0, stream>>>(qh, kh, vTh, Oh);
    gemm128<3><<<dim3(32, 8), 256, 0, stream>>>(Oh, WoT, bo, out);
}